// Round 13
// baseline (220.791 us; speedup 1.0000x reference)
//
#include <hip/hip_runtime.h>
#include <stdint.h>
#include <math.h>

#define B_ 8
#define S_ 1024
#define D0_ 128
#define D_ 256
#define H_ 8
#define HD_ 32
#define BH_ (B_*H_)

typedef __attribute__((ext_vector_type(8))) short short8;
typedef __attribute__((ext_vector_type(4))) float f32x4;
typedef __attribute__((ext_vector_type(4))) unsigned int u32x4;
typedef __attribute__((ext_vector_type(2))) float f32x2;
typedef __attribute__((ext_vector_type(4))) unsigned short u16x4;

__device__ __forceinline__ unsigned short f2bf(float x) {
    unsigned int u = __float_as_uint(x);
    u += 0x7FFFu + ((u >> 16) & 1u);
    return (unsigned short)(u >> 16);
}
__device__ __forceinline__ float bf2f(unsigned short s) {
    return __uint_as_float(((unsigned int)s) << 16);
}
// split 8 fp32 (two f32x4) into bf16 hi + lo fragments (y ~= hi + lo, err ~2^-17)
__device__ __forceinline__ void split_hi_lo(f32x4 a, f32x4 b, short8& hi, short8& lo) {
    #pragma unroll
    for (int i = 0; i < 4; ++i) {
        unsigned short h = f2bf(a[i]);
        hi[i] = (short)h; lo[i] = (short)f2bf(a[i] - bf2f(h));
    }
    #pragma unroll
    for (int i = 0; i < 4; ++i) {
        unsigned short h = f2bf(b[i]);
        hi[4 + i] = (short)h; lo[4 + i] = (short)f2bf(b[i] - bf2f(h));
    }
}

// ---------------- Kernel 1: projections via bf16 MFMA, bn-loop inside ----------------
// R12 post-mortem: MFMA proj cut total 260->219; attn pinned at 184.6 across 6
// structures (accepted plateau). This round: proj grid (128,3) = 384 fat blocks
// (bn-loop inside): X split once per (bm,z) not 4x; 4x smaller dispatch ramp;
// z=0 block covers all 8 heads -> self-contained mask epilogue.
//  z<2 (Q/K): A=W,B=X -> lane: m=mrow(c), n=g*4+r -> u16x4 hi/lo stores along d
//  z=2 (V):   A=X,B=W -> lane: m=g*4+r, n=nrow(c) -> u16x4 store along s (Vt)
__global__ __launch_bounds__(256) void proj_kernel(
    const float* __restrict__ query,
    const float* __restrict__ Wq, const float* __restrict__ Wk, const float* __restrict__ Wv,
    unsigned short* __restrict__ Qhi, unsigned short* __restrict__ Qlo,
    unsigned short* __restrict__ Khi, unsigned short* __restrict__ Klo,
    unsigned short* __restrict__ Vt, float* __restrict__ maskbias)
{
    const int z = blockIdx.y;
    const float* W = (z == 0) ? Wq : (z == 1) ? Wk : Wv;
    const int bm = blockIdx.x * 64;
    __shared__ float msum[64][8];
    const int tid = threadIdx.x;
    const int wid = tid >> 6;
    const int c = tid & 15;
    const int g = (tid >> 4) & 3;

    if (z == 0) {
        #pragma unroll
        for (int i = tid; i < 512; i += 256) ((float*)msum)[i] = 0.f;
        __syncthreads();
    }

    const int mrow = bm + wid * 16 + c;
    // X fragments (rows m, k-cols 8g..8g+7 per 32-wide k-step), hi/lo — split ONCE
    short8 xh[4], xl[4];
    #pragma unroll
    for (int kk = 0; kk < 4; ++kk) {
        f32x4 a = *(const f32x4*)(query + (size_t)mrow * 128 + kk * 32 + 8 * g);
        f32x4 b = *(const f32x4*)(query + (size_t)mrow * 128 + kk * 32 + 8 * g + 4);
        split_hi_lo(a, b, xh[kk], xl[kk]);
    }

    for (int bn = 0; bn < 256; bn += 64) {
        #pragma unroll
        for (int nt = 0; nt < 4; ++nt) {
            const int nrow = bn + nt * 16 + c;
            short8 wh[4], wl[4];
            #pragma unroll
            for (int kk = 0; kk < 4; ++kk) {
                f32x4 a = *(const f32x4*)(W + (size_t)nrow * 128 + kk * 32 + 8 * g);
                f32x4 b = *(const f32x4*)(W + (size_t)nrow * 128 + kk * 32 + 8 * g + 4);
                split_hi_lo(a, b, wh[kk], wl[kk]);
            }
            f32x4 acc = (f32x4){0.f, 0.f, 0.f, 0.f};
            if (z < 2) {
                // swapped: A=W (rows n), B=X (rows m)
                #pragma unroll
                for (int kk = 0; kk < 4; ++kk) {
                    acc = __builtin_amdgcn_mfma_f32_16x16x32_bf16(wh[kk], xh[kk], acc, 0, 0, 0);
                    acc = __builtin_amdgcn_mfma_f32_16x16x32_bf16(wl[kk], xh[kk], acc, 0, 0, 0);
                    acc = __builtin_amdgcn_mfma_f32_16x16x32_bf16(wh[kk], xl[kk], acc, 0, 0, 0);
                }
                const int b_ = mrow >> 10, s = mrow & 1023;
                const int n0 = bn + nt * 16 + g * 4;
                const int h = n0 >> 5, d0 = n0 & 31;
                const int bh = b_ * 8 + h;
                u16x4 h4, l4;
                #pragma unroll
                for (int r = 0; r < 4; ++r) {
                    unsigned short hh = f2bf(acc[r]);
                    h4[r] = hh;
                    l4[r] = f2bf(acc[r] - bf2f(hh));
                }
                size_t idx = ((size_t)(bh * 1024 + s)) * 32 + d0;
                if (z == 0) {
                    *(u16x4*)(Qhi + idx) = h4;
                    *(u16x4*)(Qlo + idx) = l4;
                    float psum = acc[0] + acc[1] + acc[2] + acc[3];
                    atomicAdd(&msum[wid * 16 + c][h], psum);
                } else {
                    *(u16x4*)(Khi + idx) = h4;
                    *(u16x4*)(Klo + idx) = l4;
                }
            } else {
                // non-swapped: A=X (rows m), B=W (rows n)
                #pragma unroll
                for (int kk = 0; kk < 4; ++kk) {
                    acc = __builtin_amdgcn_mfma_f32_16x16x32_bf16(xh[kk], wh[kk], acc, 0, 0, 0);
                    acc = __builtin_amdgcn_mfma_f32_16x16x32_bf16(xl[kk], wh[kk], acc, 0, 0, 0);
                    acc = __builtin_amdgcn_mfma_f32_16x16x32_bf16(xh[kk], wl[kk], acc, 0, 0, 0);
                }
                const int m0 = bm + wid * 16 + g * 4;
                const int b_ = m0 >> 10, s0 = m0 & 1023;
                const int n = bn + nt * 16 + c;
                const int h = n >> 5, d = n & 31;
                const int bh = b_ * 8 + h;
                u16x4 v4;
                #pragma unroll
                for (int r = 0; r < 4; ++r) v4[r] = f2bf(acc[r]);
                *(u16x4*)(Vt + ((size_t)(bh * 32 + d)) * 1024 + s0) = v4;
            }
        }
    }
    if (z == 0) {
        __syncthreads();
        #pragma unroll
        for (int i = tid; i < 512; i += 256) {
            int row = i >> 3, h = i & 7;
            int m = bm + row;
            int b_ = m >> 10, s = m & 1023;
            int bh = b_ * 8 + h;
            maskbias[bh * 1024 + s] = (msum[row][h] != 0.0f) ? 0.0f : -INFINITY;
        }
    }
}

// ---------------- Kernel 2: fused attention (R7/R12 verbatim — measured 184us) ----------------
__global__ __launch_bounds__(256, 4) void attn_kernel(
    const unsigned short* __restrict__ Qhi, const unsigned short* __restrict__ Qlo,
    const unsigned short* __restrict__ Khi, const unsigned short* __restrict__ Klo,
    const unsigned short* __restrict__ Vt, const float* __restrict__ maskbias,
    const float* __restrict__ U, float* __restrict__ attn_out, float* __restrict__ out_buf)
{
    __shared__ float Ored[4 * 16 * 36];     // [wave][q(16)][d(32)+pad4]
    __shared__ float redMS[4][2][16];       // per-wave (m_w, s_w) per q

    const int bid = blockIdx.x;
    const int swz = (bid & 7) * 512 + (bid >> 3);   // XCD-contiguous bh
    const int bh = swz >> 6;
    const int qbase = (swz & 63) << 4;
    const int tid = threadIdx.x;
    const int wid = tid >> 6;
    const int c = tid & 15;
    const int g = (tid >> 4) & 3;
    const int kstrip = wid << 8;

    const size_t bh_qk = (size_t)bh * S_ * 32;
    const size_t bh_u = (size_t)bh * S_ * S_;
    const int q = qbase + c;

    // ---- U loads straight into the score accumulators (MFMA C-init) ----
    const float* Urow = U + bh_u + (size_t)q * S_;
    f32x4 s[16];
    #pragma unroll
    for (int kf = 0; kf < 16; ++kf)
        s[kf] = *(const f32x4*)(Urow + kstrip + kf * 16 + g * 4);

    // Q fragment (B operand: col q = c, elements d = g*8..g*8+7)
    short8 qh = *(const short8*)(Qhi + bh_qk + (size_t)q * 32 + 8 * g);
    short8 ql = *(const short8*)(Qlo + bh_qk + (size_t)q * 32 + 8 * g);

    // QK^T swapped, hi/lo split (3 MFMAs per kf); C-in = U so s = qk + u
    #pragma unroll
    for (int kf = 0; kf < 16; ++kf) {
        size_t koff = bh_qk + (size_t)(kstrip + kf * 16 + c) * 32 + 8 * g;
        short8 kh = *(const short8*)(Khi + koff);
        short8 kl = *(const short8*)(Klo + koff);
        s[kf] = __builtin_amdgcn_mfma_f32_16x16x32_bf16(kh, qh, s[kf], 0, 0, 0);
        s[kf] = __builtin_amdgcn_mfma_f32_16x16x32_bf16(kl, qh, s[kf], 0, 0, 0);
        s[kf] = __builtin_amdgcn_mfma_f32_16x16x32_bf16(kh, ql, s[kf], 0, 0, 0);
    }

    const float inv_scale = 0.17677669529663687f; // 1/sqrt(32)
    const float* mbrow = maskbias + bh * S_;
    #pragma unroll
    for (int kf = 0; kf < 16; ++kf) {
        int k0 = kstrip + kf * 16 + g * 4;
        f32x4 mb = *(const f32x4*)(mbrow + k0);
        #pragma unroll
        for (int r = 0; r < 4; ++r)
            s[kf][r] = s[kf][r] * inv_scale + mb[r];
    }

    // local (per-wave) softmax stats for this q = c
    float m = s[0][0];
    #pragma unroll
    for (int kf = 0; kf < 16; ++kf)
        #pragma unroll
        for (int r = 0; r < 4; ++r) m = fmaxf(m, s[kf][r]);
    m = fmaxf(m, __shfl_xor(m, 16, 64));
    m = fmaxf(m, __shfl_xor(m, 32, 64));
    m = fmaxf(m, -1e30f);   // guard fully-masked strip

    float sum = 0.f;
    #pragma unroll
    for (int kf = 0; kf < 16; ++kf)
        #pragma unroll
        for (int r = 0; r < 4; ++r) {
            float p = __expf(s[kf][r] - m);
            s[kf][r] = p;              // p_local
            sum += p;
        }
    sum += __shfl_xor(sum, 16, 64);
    sum += __shfl_xor(sum, 32, 64);
    if (g == 0) { redMS[wid][0][c] = m; redMS[wid][1][c] = sum; }
    __syncthreads();

    // flash combine across the 4 k-strips
    float m0 = redMS[0][0][c], m1 = redMS[1][0][c], m2 = redMS[2][0][c], m3 = redMS[3][0][c];
    float M = fmaxf(fmaxf(m0, m1), fmaxf(m2, m3));
    float S = redMS[0][1][c] * __expf(m0 - M) + redMS[1][1][c] * __expf(m1 - M)
            + redMS[2][1][c] * __expf(m2 - M) + redMS[3][1][c] * __expf(m3 - M);
    const float fw = __expf(m - M) / S;   // scale for this wave's p_local

    // PV on RAW p_local; B-frags via in-wave shfl redistribution
    const int srcA = c + 32 * (g & 1);
    const int srcB = srcA + 16;
    const int gd2 = g >> 1;
    f32x4 o0 = (f32x4){0.f, 0.f, 0.f, 0.f};
    f32x4 o1 = (f32x4){0.f, 0.f, 0.f, 0.f};
    const unsigned short* vb0 = Vt + (size_t)(bh * 32 + c) * 1024 + kstrip;
    const unsigned short* vb1 = vb0 + 16 * 1024;
    #pragma unroll
    for (int ch = 0; ch < 8; ++ch) {
        unsigned int p0[2], p1[2];
        p0[0] = __builtin_amdgcn_perm(__float_as_uint(s[2 * ch][1]), __float_as_uint(s[2 * ch][0]), 0x07060302u);
        p0[1] = __builtin_amdgcn_perm(__float_as_uint(s[2 * ch][3]), __float_as_uint(s[2 * ch][2]), 0x07060302u);
        p1[0] = __builtin_amdgcn_perm(__float_as_uint(s[2 * ch + 1][1]), __float_as_uint(s[2 * ch + 1][0]), 0x07060302u);
        p1[1] = __builtin_amdgcn_perm(__float_as_uint(s[2 * ch + 1][3]), __float_as_uint(s[2 * ch + 1][2]), 0x07060302u);
        unsigned int b0A = (unsigned int)__shfl((int)p0[0], srcA, 64);
        unsigned int b1A = (unsigned int)__shfl((int)p0[1], srcA, 64);
        unsigned int b0B = (unsigned int)__shfl((int)p0[0], srcB, 64);
        unsigned int b1B = (unsigned int)__shfl((int)p0[1], srcB, 64);
        unsigned int c0A = (unsigned int)__shfl((int)p1[0], srcA, 64);
        unsigned int c1A = (unsigned int)__shfl((int)p1[1], srcA, 64);
        unsigned int c0B = (unsigned int)__shfl((int)p1[0], srcB, 64);
        unsigned int c1B = (unsigned int)__shfl((int)p1[1], srcB, 64);
        union { u32x4 u; short8 h; } bb;
        bb.u[0] = gd2 ? c0A : b0A;
        bb.u[1] = gd2 ? c1A : b1A;
        bb.u[2] = gd2 ? c0B : b0B;
        bb.u[3] = gd2 ? c1B : b1B;
        short8 A0 = *(const short8*)(vb0 + ch * 32 + g * 8);
        short8 A1 = *(const short8*)(vb1 + ch * 32 + g * 8);
        o0 = __builtin_amdgcn_mfma_f32_16x16x32_bf16(A0, bb.h, o0, 0, 0, 0);
        o1 = __builtin_amdgcn_mfma_f32_16x16x32_bf16(A1, bb.h, o1, 0, 0, 0);
    }
    // scale by fw (PV col = q = c matches fw's q), then cross-wave reduce
    #pragma unroll
    for (int r = 0; r < 4; ++r) { o0[r] *= fw; o1[r] *= fw; }
    *(f32x4*)(&Ored[(wid * 16 + c) * 36 + g * 4]) = o0;
    *(f32x4*)(&Ored[(wid * 16 + c) * 36 + 16 + g * 4]) = o1;
    __syncthreads();

    // final 4-way reduce + store: thread t -> q = t>>4, d-pair = (t&15)*2
    const int qq = tid >> 4;
    const int dd = (tid & 15) * 2;
    float v0 = 0.f, v1 = 0.f;
    #pragma unroll
    for (int w = 0; w < 4; ++w) {
        v0 += Ored[(w * 16 + qq) * 36 + dd];
        v1 += Ored[(w * 16 + qq) * 36 + dd + 1];
    }
    const int b = bh >> 3, h = bh & 7;
    f32x2 vv = {v0, v1};
    *(f32x2*)(out_buf + ((size_t)(b * 1024 + qbase + qq)) * 256 + h * 32 + dd) = vv;

    // ---- tail: normalize + store attn (fire-and-forget, no barrier after) ----
    float* arow = attn_out + bh_u + (size_t)q * S_;
    #pragma unroll
    for (int kf = 0; kf < 16; ++kf) {
        int k0 = kstrip + kf * 16 + g * 4;
        f32x4 a;
        #pragma unroll
        for (int r = 0; r < 4; ++r) a[r] = s[kf][r] * fw;
        *(f32x4*)(arow + k0) = a;
    }
}

// ---------------- Kernel 3: output projection via bf16 MFMA (hi/lo) ----------------
__global__ __launch_bounds__(256) void outproj_kernel(
    const float* __restrict__ xb, const float* __restrict__ Wo, float* __restrict__ outp)
{
    const int bm = blockIdx.x * 64;
    const int bn = blockIdx.y * 64;
    const int tid = threadIdx.x;
    const int wid = tid >> 6, c = tid & 15, g = (tid >> 4) & 3;
    const int mrow = bm + wid * 16 + c;

    short8 xh[8], xl[8];
    #pragma unroll
    for (int kk = 0; kk < 8; ++kk) {
        f32x4 a = *(const f32x4*)(xb + (size_t)mrow * 256 + kk * 32 + 8 * g);
        f32x4 b = *(const f32x4*)(xb + (size_t)mrow * 256 + kk * 32 + 8 * g + 4);
        split_hi_lo(a, b, xh[kk], xl[kk]);
    }
    #pragma unroll
    for (int nt = 0; nt < 4; ++nt) {
        const int nrow = bn + nt * 16 + c;
        f32x4 acc = (f32x4){0.f, 0.f, 0.f, 0.f};
        #pragma unroll
        for (int kk = 0; kk < 8; ++kk) {
            f32x4 a = *(const f32x4*)(Wo + (size_t)nrow * 256 + kk * 32 + 8 * g);
            f32x4 b = *(const f32x4*)(Wo + (size_t)nrow * 256 + kk * 32 + 8 * g + 4);
            short8 wh, wl;
            split_hi_lo(a, b, wh, wl);
            acc = __builtin_amdgcn_mfma_f32_16x16x32_bf16(wh, xh[kk], acc, 0, 0, 0);
            acc = __builtin_amdgcn_mfma_f32_16x16x32_bf16(wl, xh[kk], acc, 0, 0, 0);
            acc = __builtin_amdgcn_mfma_f32_16x16x32_bf16(wh, xl[kk], acc, 0, 0, 0);
        }
        *(f32x4*)(outp + (size_t)mrow * 128 + bn + nt * 16 + g * 4) = acc;
    }
}

extern "C" void kernel_launch(void* const* d_in, const int* in_sizes, int n_in,
                              void* d_out, int out_size, void* d_ws, size_t ws_size,
                              hipStream_t stream)
{
    const float* query = (const float*)d_in[0];
    const float* U     = (const float*)d_in[1];
    const float* Wq    = (const float*)d_in[2];
    const float* Wk    = (const float*)d_in[3];
    const float* Wv    = (const float*)d_in[4];
    const float* Wo    = (const float*)d_in[5];

    float* output = (float*)d_out;                                 // B*S*D0
    float* attn   = (float*)d_out + (size_t)B_ * S_ * D0_;         // B*H*S*S

    const size_t NQK = (size_t)BH_ * S_ * 32;
    unsigned short* Qhi = (unsigned short*)d_ws;
    unsigned short* Qlo = Qhi + NQK;
    unsigned short* Khi = Qlo + NQK;
    unsigned short* Klo = Khi + NQK;
    unsigned short* Vt  = Klo + NQK;
    float* maskbias = (float*)(Vt + NQK);
    float* out_buf  = maskbias + (size_t)BH_ * S_;

    proj_kernel<<<dim3(128, 3), 256, 0, stream>>>(query, Wq, Wk, Wv, Qhi, Qlo, Khi, Klo, Vt, maskbias);
    attn_kernel<<<dim3(4096), 256, 0, stream>>>(Qhi, Qlo, Khi, Klo, Vt, maskbias, U, attn, out_buf);
    outproj_kernel<<<dim3(128, 2), 256, 0, stream>>>(out_buf, Wo, output);
}

// Round 14
// 219.052 us; speedup vs baseline: 1.0079x; 1.0079x over previous
//
#include <hip/hip_runtime.h>
#include <stdint.h>
#include <math.h>

#define B_ 8
#define S_ 1024
#define D0_ 128
#define D_ 256
#define H_ 8
#define HD_ 32
#define BH_ (B_*H_)

typedef __attribute__((ext_vector_type(8))) short short8;
typedef __attribute__((ext_vector_type(4))) float f32x4;
typedef __attribute__((ext_vector_type(4))) unsigned int u32x4;
typedef __attribute__((ext_vector_type(2))) float f32x2;
typedef __attribute__((ext_vector_type(4))) unsigned short u16x4;

__device__ __forceinline__ unsigned short f2bf(float x) {
    unsigned int u = __float_as_uint(x);
    u += 0x7FFFu + ((u >> 16) & 1u);
    return (unsigned short)(u >> 16);
}
__device__ __forceinline__ float bf2f(unsigned short s) {
    return __uint_as_float(((unsigned int)s) << 16);
}
// split 8 fp32 (two f32x4) into bf16 hi + lo fragments (y ~= hi + lo, err ~2^-17)
__device__ __forceinline__ void split_hi_lo(f32x4 a, f32x4 b, short8& hi, short8& lo) {
    #pragma unroll
    for (int i = 0; i < 4; ++i) {
        unsigned short h = f2bf(a[i]);
        hi[i] = (short)h; lo[i] = (short)f2bf(a[i] - bf2f(h));
    }
    #pragma unroll
    for (int i = 0; i < 4; ++i) {
        unsigned short h = f2bf(b[i]);
        hi[4 + i] = (short)h; lo[4 + i] = (short)f2bf(b[i] - bf2f(h));
    }
}

// ---------------- Kernel 1: projections via bf16 MFMA (hi/lo split) ----------------
// Final configuration (R12): Y = XhWh+XlWh+XhWl (drop XlWl, ~2e-4 abs err).
//  z<2 (Q/K): A=W,B=X -> lane holds m=c, n=g*4+r -> u16x4 hi/lo stores along d
//  z=2 (V):   A=X,B=W -> lane holds m=g*4+r, n=c -> u16x4 store along s (Vt)
// Mask rowsums fused in z=0 epilogue.
__global__ __launch_bounds__(256) void proj_kernel(
    const float* __restrict__ query,
    const float* __restrict__ Wq, const float* __restrict__ Wk, const float* __restrict__ Wv,
    unsigned short* __restrict__ Qhi, unsigned short* __restrict__ Qlo,
    unsigned short* __restrict__ Khi, unsigned short* __restrict__ Klo,
    unsigned short* __restrict__ Vt, float* __restrict__ maskbias)
{
    const int z = blockIdx.z;
    const float* W = (z == 0) ? Wq : (z == 1) ? Wk : Wv;
    const int bm = blockIdx.x * 64;
    const int bn = blockIdx.y * 64;
    __shared__ float msum[64][2];
    const int tid = threadIdx.x;
    const int wid = tid >> 6;
    const int c = tid & 15;
    const int g = (tid >> 4) & 3;

    if (z == 0) {
        if (tid < 128) msum[tid >> 1][tid & 1] = 0.f;
        __syncthreads();
    }

    const int mrow = bm + wid * 16 + c;
    // X fragments (rows m, k-cols 8g..8g+7 per 32-wide k-step), hi/lo
    short8 xh[4], xl[4];
    #pragma unroll
    for (int kk = 0; kk < 4; ++kk) {
        f32x4 a = *(const f32x4*)(query + (size_t)mrow * 128 + kk * 32 + 8 * g);
        f32x4 b = *(const f32x4*)(query + (size_t)mrow * 128 + kk * 32 + 8 * g + 4);
        split_hi_lo(a, b, xh[kk], xl[kk]);
    }

    float ph0 = 0.f, ph1 = 0.f;
    #pragma unroll
    for (int nt = 0; nt < 4; ++nt) {
        const int nrow = bn + nt * 16 + c;
        short8 wh[4], wl[4];
        #pragma unroll
        for (int kk = 0; kk < 4; ++kk) {
            f32x4 a = *(const f32x4*)(W + (size_t)nrow * 128 + kk * 32 + 8 * g);
            f32x4 b = *(const f32x4*)(W + (size_t)nrow * 128 + kk * 32 + 8 * g + 4);
            split_hi_lo(a, b, wh[kk], wl[kk]);
        }
        f32x4 acc = (f32x4){0.f, 0.f, 0.f, 0.f};
        if (z < 2) {
            // swapped: A=W (rows n), B=X (rows m) -> lane: m=mrow, n=bn+16nt+g*4+r
            #pragma unroll
            for (int kk = 0; kk < 4; ++kk) {
                acc = __builtin_amdgcn_mfma_f32_16x16x32_bf16(wh[kk], xh[kk], acc, 0, 0, 0);
                acc = __builtin_amdgcn_mfma_f32_16x16x32_bf16(wl[kk], xh[kk], acc, 0, 0, 0);
                acc = __builtin_amdgcn_mfma_f32_16x16x32_bf16(wh[kk], xl[kk], acc, 0, 0, 0);
            }
            const int b_ = mrow >> 10, s = mrow & 1023;
            const int n0 = bn + nt * 16 + g * 4;
            const int h = n0 >> 5, d0 = n0 & 31;
            const int bh = b_ * 8 + h;
            u16x4 h4, l4;
            #pragma unroll
            for (int r = 0; r < 4; ++r) {
                unsigned short hh = f2bf(acc[r]);
                h4[r] = hh;
                l4[r] = f2bf(acc[r] - bf2f(hh));
            }
            size_t idx = ((size_t)(bh * 1024 + s)) * 32 + d0;
            if (z == 0) {
                *(u16x4*)(Qhi + idx) = h4;
                *(u16x4*)(Qlo + idx) = l4;
                float psum = acc[0] + acc[1] + acc[2] + acc[3];
                if (nt < 2) ph0 += psum; else ph1 += psum;
            } else {
                *(u16x4*)(Khi + idx) = h4;
                *(u16x4*)(Klo + idx) = l4;
            }
        } else {
            // non-swapped: A=X (rows m), B=W (rows n) -> lane: m=bm+16w+g*4+r, n=nrow
            #pragma unroll
            for (int kk = 0; kk < 4; ++kk) {
                acc = __builtin_amdgcn_mfma_f32_16x16x32_bf16(xh[kk], wh[kk], acc, 0, 0, 0);
                acc = __builtin_amdgcn_mfma_f32_16x16x32_bf16(xl[kk], wh[kk], acc, 0, 0, 0);
                acc = __builtin_amdgcn_mfma_f32_16x16x32_bf16(xh[kk], wl[kk], acc, 0, 0, 0);
            }
            const int m0 = bm + wid * 16 + g * 4;
            const int b_ = m0 >> 10, s0 = m0 & 1023;
            const int n = bn + nt * 16 + c;
            const int h = n >> 5, d = n & 31;
            const int bh = b_ * 8 + h;
            u16x4 v4;
            #pragma unroll
            for (int r = 0; r < 4; ++r) v4[r] = f2bf(acc[r]);
            *(u16x4*)(Vt + ((size_t)(bh * 32 + d)) * 1024 + s0) = v4;
        }
    }
    if (z == 0) {
        atomicAdd(&msum[wid * 16 + c][0], ph0);
        atomicAdd(&msum[wid * 16 + c][1], ph1);
        __syncthreads();
        if (tid < 128) {
            int row = tid >> 1, hh = tid & 1;
            int m = bm + row;
            int b_ = m >> 10, s = m & 1023;
            int bh = b_ * 8 + (bn >> 5) + hh;
            maskbias[bh * 1024 + s] = (msum[row][hh] != 0.0f) ? 0.0f : -INFINITY;
        }
    }
}

// ---------------- Kernel 2: fused attention (R7 structure — empirical plateau 184us) ----------------
// 7 structural variants (R5-R11) all measured 184-200us at identical 424MB
// traffic, insensitive to occupancy 22-63%, DMA vs scatter, store placement.
// This is the best-measured form.
__global__ __launch_bounds__(256, 4) void attn_kernel(
    const unsigned short* __restrict__ Qhi, const unsigned short* __restrict__ Qlo,
    const unsigned short* __restrict__ Khi, const unsigned short* __restrict__ Klo,
    const unsigned short* __restrict__ Vt, const float* __restrict__ maskbias,
    const float* __restrict__ U, float* __restrict__ attn_out, float* __restrict__ out_buf)
{
    __shared__ float Ored[4 * 16 * 36];     // [wave][q(16)][d(32)+pad4]
    __shared__ float redMS[4][2][16];       // per-wave (m_w, s_w) per q

    const int bid = blockIdx.x;
    const int swz = (bid & 7) * 512 + (bid >> 3);   // XCD-contiguous bh
    const int bh = swz >> 6;
    const int qbase = (swz & 63) << 4;
    const int tid = threadIdx.x;
    const int wid = tid >> 6;
    const int c = tid & 15;
    const int g = (tid >> 4) & 3;
    const int kstrip = wid << 8;

    const size_t bh_qk = (size_t)bh * S_ * 32;
    const size_t bh_u = (size_t)bh * S_ * S_;
    const int q = qbase + c;

    // ---- U loads straight into the score accumulators (MFMA C-init) ----
    const float* Urow = U + bh_u + (size_t)q * S_;
    f32x4 s[16];
    #pragma unroll
    for (int kf = 0; kf < 16; ++kf)
        s[kf] = *(const f32x4*)(Urow + kstrip + kf * 16 + g * 4);

    // Q fragment (B operand: col q = c, elements d = g*8..g*8+7)
    short8 qh = *(const short8*)(Qhi + bh_qk + (size_t)q * 32 + 8 * g);
    short8 ql = *(const short8*)(Qlo + bh_qk + (size_t)q * 32 + 8 * g);

    // QK^T swapped, hi/lo split (3 MFMAs per kf); C-in = U so s = qk + u
    #pragma unroll
    for (int kf = 0; kf < 16; ++kf) {
        size_t koff = bh_qk + (size_t)(kstrip + kf * 16 + c) * 32 + 8 * g;
        short8 kh = *(const short8*)(Khi + koff);
        short8 kl = *(const short8*)(Klo + koff);
        s[kf] = __builtin_amdgcn_mfma_f32_16x16x32_bf16(kh, qh, s[kf], 0, 0, 0);
        s[kf] = __builtin_amdgcn_mfma_f32_16x16x32_bf16(kl, qh, s[kf], 0, 0, 0);
        s[kf] = __builtin_amdgcn_mfma_f32_16x16x32_bf16(kh, ql, s[kf], 0, 0, 0);
    }

    const float inv_scale = 0.17677669529663687f; // 1/sqrt(32)
    const float* mbrow = maskbias + bh * S_;
    #pragma unroll
    for (int kf = 0; kf < 16; ++kf) {
        int k0 = kstrip + kf * 16 + g * 4;
        f32x4 mb = *(const f32x4*)(mbrow + k0);
        #pragma unroll
        for (int r = 0; r < 4; ++r)
            s[kf][r] = s[kf][r] * inv_scale + mb[r];
    }

    // local (per-wave) softmax stats for this q = c
    float m = s[0][0];
    #pragma unroll
    for (int kf = 0; kf < 16; ++kf)
        #pragma unroll
        for (int r = 0; r < 4; ++r) m = fmaxf(m, s[kf][r]);
    m = fmaxf(m, __shfl_xor(m, 16, 64));
    m = fmaxf(m, __shfl_xor(m, 32, 64));
    m = fmaxf(m, -1e30f);   // guard fully-masked strip

    float sum = 0.f;
    #pragma unroll
    for (int kf = 0; kf < 16; ++kf)
        #pragma unroll
        for (int r = 0; r < 4; ++r) {
            float p = __expf(s[kf][r] - m);
            s[kf][r] = p;              // p_local
            sum += p;
        }
    sum += __shfl_xor(sum, 16, 64);
    sum += __shfl_xor(sum, 32, 64);
    if (g == 0) { redMS[wid][0][c] = m; redMS[wid][1][c] = sum; }
    __syncthreads();

    // flash combine across the 4 k-strips
    float m0 = redMS[0][0][c], m1 = redMS[1][0][c], m2 = redMS[2][0][c], m3 = redMS[3][0][c];
    float M = fmaxf(fmaxf(m0, m1), fmaxf(m2, m3));
    float S = redMS[0][1][c] * __expf(m0 - M) + redMS[1][1][c] * __expf(m1 - M)
            + redMS[2][1][c] * __expf(m2 - M) + redMS[3][1][c] * __expf(m3 - M);
    const float fw = __expf(m - M) / S;   // scale for this wave's p_local

    // PV on RAW p_local; B-frags via in-wave shfl redistribution
    const int srcA = c + 32 * (g & 1);
    const int srcB = srcA + 16;
    const int gd2 = g >> 1;
    f32x4 o0 = (f32x4){0.f, 0.f, 0.f, 0.f};
    f32x4 o1 = (f32x4){0.f, 0.f, 0.f, 0.f};
    const unsigned short* vb0 = Vt + (size_t)(bh * 32 + c) * 1024 + kstrip;
    const unsigned short* vb1 = vb0 + 16 * 1024;
    #pragma unroll
    for (int ch = 0; ch < 8; ++ch) {
        unsigned int p0[2], p1[2];
        p0[0] = __builtin_amdgcn_perm(__float_as_uint(s[2 * ch][1]), __float_as_uint(s[2 * ch][0]), 0x07060302u);
        p0[1] = __builtin_amdgcn_perm(__float_as_uint(s[2 * ch][3]), __float_as_uint(s[2 * ch][2]), 0x07060302u);
        p1[0] = __builtin_amdgcn_perm(__float_as_uint(s[2 * ch + 1][1]), __float_as_uint(s[2 * ch + 1][0]), 0x07060302u);
        p1[1] = __builtin_amdgcn_perm(__float_as_uint(s[2 * ch + 1][3]), __float_as_uint(s[2 * ch + 1][2]), 0x07060302u);
        unsigned int b0A = (unsigned int)__shfl((int)p0[0], srcA, 64);
        unsigned int b1A = (unsigned int)__shfl((int)p0[1], srcA, 64);
        unsigned int b0B = (unsigned int)__shfl((int)p0[0], srcB, 64);
        unsigned int b1B = (unsigned int)__shfl((int)p0[1], srcB, 64);
        unsigned int c0A = (unsigned int)__shfl((int)p1[0], srcA, 64);
        unsigned int c1A = (unsigned int)__shfl((int)p1[1], srcA, 64);
        unsigned int c0B = (unsigned int)__shfl((int)p1[0], srcB, 64);
        unsigned int c1B = (unsigned int)__shfl((int)p1[1], srcB, 64);
        union { u32x4 u; short8 h; } bb;
        bb.u[0] = gd2 ? c0A : b0A;
        bb.u[1] = gd2 ? c1A : b1A;
        bb.u[2] = gd2 ? c0B : b0B;
        bb.u[3] = gd2 ? c1B : b1B;
        short8 A0 = *(const short8*)(vb0 + ch * 32 + g * 8);
        short8 A1 = *(const short8*)(vb1 + ch * 32 + g * 8);
        o0 = __builtin_amdgcn_mfma_f32_16x16x32_bf16(A0, bb.h, o0, 0, 0, 0);
        o1 = __builtin_amdgcn_mfma_f32_16x16x32_bf16(A1, bb.h, o1, 0, 0, 0);
    }
    // scale by fw (PV col = q = c matches fw's q), then cross-wave reduce
    #pragma unroll
    for (int r = 0; r < 4; ++r) { o0[r] *= fw; o1[r] *= fw; }
    *(f32x4*)(&Ored[(wid * 16 + c) * 36 + g * 4]) = o0;
    *(f32x4*)(&Ored[(wid * 16 + c) * 36 + 16 + g * 4]) = o1;
    __syncthreads();

    // final 4-way reduce + store: thread t -> q = t>>4, d-pair = (t&15)*2
    const int qq = tid >> 4;
    const int dd = (tid & 15) * 2;
    float v0 = 0.f, v1 = 0.f;
    #pragma unroll
    for (int w = 0; w < 4; ++w) {
        v0 += Ored[(w * 16 + qq) * 36 + dd];
        v1 += Ored[(w * 16 + qq) * 36 + dd + 1];
    }
    const int b = bh >> 3, h = bh & 7;
    f32x2 vv = {v0, v1};
    *(f32x2*)(out_buf + ((size_t)(b * 1024 + qbase + qq)) * 256 + h * 32 + dd) = vv;

    // ---- tail: normalize + store attn (fire-and-forget, no barrier after) ----
    float* arow = attn_out + bh_u + (size_t)q * S_;
    #pragma unroll
    for (int kf = 0; kf < 16; ++kf) {
        int k0 = kstrip + kf * 16 + g * 4;
        f32x4 a;
        #pragma unroll
        for (int r = 0; r < 4; ++r) a[r] = s[kf][r] * fw;
        *(f32x4*)(arow + k0) = a;
    }
}

// ---------------- Kernel 3: output projection via bf16 MFMA (hi/lo) ----------------
__global__ __launch_bounds__(256) void outproj_kernel(
    const float* __restrict__ xb, const float* __restrict__ Wo, float* __restrict__ outp)
{
    const int bm = blockIdx.x * 64;
    const int bn = blockIdx.y * 64;
    const int tid = threadIdx.x;
    const int wid = tid >> 6, c = tid & 15, g = (tid >> 4) & 3;
    const int mrow = bm + wid * 16 + c;

    short8 xh[8], xl[8];
    #pragma unroll
    for (int kk = 0; kk < 8; ++kk) {
        f32x4 a = *(const f32x4*)(xb + (size_t)mrow * 256 + kk * 32 + 8 * g);
        f32x4 b = *(const f32x4*)(xb + (size_t)mrow * 256 + kk * 32 + 8 * g + 4);
        split_hi_lo(a, b, xh[kk], xl[kk]);
    }
    #pragma unroll
    for (int nt = 0; nt < 4; ++nt) {
        const int nrow = bn + nt * 16 + c;
        f32x4 acc = (f32x4){0.f, 0.f, 0.f, 0.f};
        #pragma unroll
        for (int kk = 0; kk < 8; ++kk) {
            f32x4 a = *(const f32x4*)(Wo + (size_t)nrow * 256 + kk * 32 + 8 * g);
            f32x4 b = *(const f32x4*)(Wo + (size_t)nrow * 256 + kk * 32 + 8 * g + 4);
            short8 wh, wl;
            split_hi_lo(a, b, wh, wl);
            acc = __builtin_amdgcn_mfma_f32_16x16x32_bf16(wh, xh[kk], acc, 0, 0, 0);
            acc = __builtin_amdgcn_mfma_f32_16x16x32_bf16(wl, xh[kk], acc, 0, 0, 0);
            acc = __builtin_amdgcn_mfma_f32_16x16x32_bf16(wh, xl[kk], acc, 0, 0, 0);
        }
        *(f32x4*)(outp + (size_t)mrow * 128 + bn + nt * 16 + g * 4) = acc;
    }
}

extern "C" void kernel_launch(void* const* d_in, const int* in_sizes, int n_in,
                              void* d_out, int out_size, void* d_ws, size_t ws_size,
                              hipStream_t stream)
{
    const float* query = (const float*)d_in[0];
    const float* U     = (const float*)d_in[1];
    const float* Wq    = (const float*)d_in[2];
    const float* Wk    = (const float*)d_in[3];
    const float* Wv    = (const float*)d_in[4];
    const float* Wo    = (const float*)d_in[5];

    float* output = (float*)d_out;                                 // B*S*D0
    float* attn   = (float*)d_out + (size_t)B_ * S_ * D0_;         // B*H*S*S

    const size_t NQK = (size_t)BH_ * S_ * 32;
    unsigned short* Qhi = (unsigned short*)d_ws;
    unsigned short* Qlo = Qhi + NQK;
    unsigned short* Khi = Qlo + NQK;
    unsigned short* Klo = Khi + NQK;
    unsigned short* Vt  = Klo + NQK;
    float* maskbias = (float*)(Vt + NQK);
    float* out_buf  = maskbias + (size_t)BH_ * S_;

    proj_kernel<<<dim3(128, 4, 3), 256, 0, stream>>>(query, Wq, Wk, Wv, Qhi, Qlo, Khi, Klo, Vt, maskbias);
    attn_kernel<<<dim3(4096), 256, 0, stream>>>(Qhi, Qlo, Khi, Klo, Vt, maskbias, U, attn, out_buf);
    outproj_kernel<<<dim3(128, 2), 256, 0, stream>>>(out_buf, Wo, output);
}